// Round 1
// baseline (702.782 us; speedup 1.0000x reference)
//
#include <hip/hip_runtime.h>

#define B_DIM 32
#define L_DIM 512
#define D_DIM 768
#define N_PROMPT 20
#define D4 (D_DIM / 4)                    // 192 float4 per (b,l) row
#define TOTAL4 (B_DIM * L_DIM * D4)       // 3,145,728 float4
#define COPY_BLOCK 256
#define COPY_GRID 2048
#define COPY_ITERS (TOTAL4 / (COPY_BLOCK * COPY_GRID))   // = 6 exactly

// Kernel A: pure streaming copy of input_embeds -> out_embeds.
// No branches, no index math beyond the stride walk; 6 independent
// float4 loads in flight per thread.
__global__ __launch_bounds__(COPY_BLOCK) void copy_kernel(
        const float4* __restrict__ in, float4* __restrict__ out) {
    size_t idx = (size_t)blockIdx.x * COPY_BLOCK + threadIdx.x;
    const size_t stride = (size_t)COPY_GRID * COPY_BLOCK;
#pragma unroll
    for (int i = 0; i < COPY_ITERS; ++i) {
        out[idx + i * stride] = in[idx + i * stride];
    }
}

// Kernel B: per-row pad-rank scan + prompt-row scatter + mask write.
// One block (256 threads) per batch row. Wave 0 does the ballot scan
// over the 512 mask entries (8 chunks of 64), records the <=20 take
// positions in LDS, then all 256 threads scatter the prompt rows
// (overwriting what kernel A copied there — stream order guarantees
// this runs after the copy).
__global__ __launch_bounds__(256) void scan_scatter_kernel(
        const int* __restrict__ mask,
        const int* __restrict__ sids,
        const float4* __restrict__ prompts,
        float4* __restrict__ out_embeds,
        float* __restrict__ out_mask) {
    const int b    = blockIdx.x;        // 0..31
    const int tid  = threadIdx.x;       // 0..255
    const int lane = tid & 63;
    const int wave = tid >> 6;

    __shared__ int s_pos[N_PROMPT];
    __shared__ int s_cnt;

    const int row_off = b * L_DIM;

    if (wave == 0) {
        int base = 0;                   // running pad count in this row
        for (int chunk = 0; chunk < L_DIM; chunk += 64) {
            const int l = chunk + lane;
            const int m = mask[row_off + l];
            const bool pad = (m == 0);
            const unsigned long long bal = __ballot(pad);
            const unsigned long long lower =
                bal & ((1ULL << lane) - 1ULL);      // lane 0 -> 0
            const int rank = base + __popcll(lower); // 0-based among pads
            const bool take = pad && (rank < N_PROMPT);
            out_mask[row_off + l] = take ? 1.0f : (float)m;
            if (take) s_pos[rank] = l;
            base += __popcll(bal);
        }
        if (lane == 0) s_cnt = (base < N_PROMPT) ? base : N_PROMPT;
    }
    __syncthreads();

    const int cnt = s_cnt;              // number of prompt rows to insert
    if (cnt == 0) return;
    const int sid = sids[b];
    const size_t pbase = (size_t)sid * N_PROMPT * D4;

    const int total = cnt * D4;         // <= 20*192 = 3840 float4
    for (int i = tid; i < total; i += 256) {
        const int k = i / D4;           // prompt row (== rank)
        const int d = i - k * D4;
        out_embeds[((size_t)(row_off + s_pos[k])) * D4 + d] =
            prompts[pbase + (size_t)k * D4 + d];
    }
}

extern "C" void kernel_launch(void* const* d_in, const int* in_sizes, int n_in,
                              void* d_out, int out_size, void* d_ws, size_t ws_size,
                              hipStream_t stream) {
    const int*   sids    = (const int*)d_in[0];    // [B] sample ids
    const float* embeds  = (const float*)d_in[1];  // [B,L,D]
    const int*   mask    = (const int*)d_in[2];    // [B,L]
    const float* prompts = (const float*)d_in[3];  // [N_SAMPLES, N_PROMPT, D]

    float* out_embeds = (float*)d_out;                               // [B,L,D]
    float* out_mask   = out_embeds + (size_t)B_DIM * L_DIM * D_DIM;  // [B,L]

    // Kernel A: branch-free bulk copy (runs first; no dependencies).
    copy_kernel<<<COPY_GRID, COPY_BLOCK, 0, stream>>>(
        (const float4*)embeds, (float4*)out_embeds);

    // Kernel B: tiny scan + scatter, serialized after A by stream order.
    scan_scatter_kernel<<<B_DIM, 256, 0, stream>>>(
        mask, sids, (const float4*)prompts, (float4*)out_embeds, out_mask);
}

// Round 2
// 689.315 us; speedup vs baseline: 1.0195x; 1.0195x over previous
//
#include <hip/hip_runtime.h>

#define B_DIM 32
#define L_DIM 512
#define D_DIM 768
#define N_PROMPT 20
#define D4 (D_DIM / 4)          // 192 float4 per (b,l) row
#define SEGS 64                 // blocks per batch row
#define ROWS_PB (L_DIM / SEGS)  // 8 l-rows per block
#define BLOCK 256
// per block: ROWS_PB * D4 = 1536 float4; per wave: 384 = 6 * 64

// Single fused kernel:
//  - all 4 waves redundantly ballot-scan the full 512-entry mask row
//    (8 chunks of 64) computing pad-rank prefix; each lane keeps the
//    take-rank for its one l in the block's chunk (s_mine).
//  - wave 0 writes the attention-mask output for the block's 8 rows.
//  - copy phase: each wave streams 2 rows (6 x 64 float4), pulling the
//    row's rank via __shfl (uniform source lane -> uniform branch),
//    reading either the prompt row or the input row. No LDS, no
//    barriers, no workspace, one launch.
__global__ __launch_bounds__(BLOCK) void fused_kernel(
        const int* __restrict__ mask,
        const int* __restrict__ sids,
        const float4* __restrict__ embeds,
        const float4* __restrict__ prompts,
        float4* __restrict__ out_embeds,
        float* __restrict__ out_mask) {
    const int blk  = blockIdx.x;
    const int b    = blk >> 6;          // blk / SEGS
    const int seg  = blk & 63;          // blk % SEGS
    const int tid  = threadIdx.x;
    const int lane = tid & 63;
    const int wave = tid >> 6;

    const int row_off    = b * L_DIM;
    const int chunk_mine = seg >> 3;         // 64-chunk containing our 8 rows
    const int sub        = (seg & 7) * 8;    // lane offset of our row 0 in chunk

    // --- full-row pad-rank scan (redundant per wave; register-only) ---
    int base   = 0;
    int s_mine = -1;
    for (int chunk = 0; chunk < 8; ++chunk) {
        const int l   = (chunk << 6) + lane;
        const int m   = mask[row_off + l];
        const bool pad = (m == 0);
        const unsigned long long bal = __ballot(pad);
        const int rank = base + __popcll(bal & ((1ULL << lane) - 1ULL));
        const bool take = pad && (rank < N_PROMPT);
        if (chunk == chunk_mine) {
            s_mine = take ? rank : -1;
            if (wave == 0 && lane >= sub && lane < sub + ROWS_PB)
                out_mask[row_off + l] = take ? 1.0f : (float)m;
        }
        base += __popcll(bal);
    }

    const int sid = sids[b];
    const size_t pbase = (size_t)sid * (N_PROMPT * D4);
    const size_t obase = ((size_t)(row_off + seg * ROWS_PB)) * D4;

    // --- copy phase: wave w owns rows [2w, 2w+2), 6 iterations of 64 ---
#pragma unroll
    for (int it = 0; it < 6; ++it) {
        const int row = wave * 2 + it / 3;        // 0..7 within block
        const int off = (it % 3) * 64 + lane;     // 0..191 within row
        const int s   = __shfl(s_mine, sub + row); // wave-uniform rank or -1
        const size_t oidx = obase + (size_t)row * D4 + off;
        float4 v;
        if (s >= 0) v = prompts[pbase + (size_t)s * D4 + off];
        else        v = embeds[oidx];
        out_embeds[oidx] = v;
    }
}

extern "C" void kernel_launch(void* const* d_in, const int* in_sizes, int n_in,
                              void* d_out, int out_size, void* d_ws, size_t ws_size,
                              hipStream_t stream) {
    const int*   sids    = (const int*)d_in[0];    // [B] sample ids
    const float* embeds  = (const float*)d_in[1];  // [B,L,D]
    const int*   mask    = (const int*)d_in[2];    // [B,L]
    const float* prompts = (const float*)d_in[3];  // [N_SAMPLES, N_PROMPT, D]

    float* out_embeds = (float*)d_out;                               // [B,L,D]
    float* out_mask   = out_embeds + (size_t)B_DIM * L_DIM * D_DIM;  // [B,L]

    fused_kernel<<<B_DIM * SEGS, BLOCK, 0, stream>>>(
        mask, sids, (const float4*)embeds, (const float4*)prompts,
        (float4*)out_embeds, out_mask);
}